// Round 2
// baseline (145.327 us; speedup 1.0000x reference)
//
#include <hip/hip_runtime.h>
#include <hip/hip_bf16.h>

typedef unsigned short u16x8 __attribute__((ext_vector_type(8)));
typedef __bf16 bf16x8 __attribute__((ext_vector_type(8)));
typedef float f32x4 __attribute__((ext_vector_type(4)));

#define NODE_DIM 128
#define HID 64

__device__ __forceinline__ unsigned short f2bf(float f) {
  union { float f; unsigned int u; } v; v.f = f;
  unsigned int u = v.u;
  u += 0x7fffu + ((u >> 16) & 1u);   // round-to-nearest-even
  return (unsigned short)(u >> 16);
}
__device__ __forceinline__ float bf2f(unsigned short s) {
  union { unsigned int u; float f; } v; v.u = ((unsigned int)s) << 16;
  return v.f;
}

// Repack W1 (256x64 row-major fp32) into Wt[j][k] bf16, j,k in [0,128):
//   j<64 : Wt[j][k] = W1[k][j]        (first half of concat -> x[row])
//   j>=64: Wt[j][k] = W1[k+128][j-64] (second half          -> x[col])
__global__ void prep_wt(const float* __restrict__ W1, unsigned short* __restrict__ Wt) {
  for (int i = blockIdx.x * blockDim.x + threadIdx.x; i < 128 * 128;
       i += gridDim.x * blockDim.x) {
    int j = i >> 7, k = i & 127;
    float w = (j < 64) ? W1[k * 64 + j] : W1[(k + 128) * 64 + (j - 64)];
    Wt[i] = f2bf(w);
  }
}

// PQ[n][j] = sum_k x[n][k] * Wt[j][k]
// LDS-free: A fragments straight from global x (fp32->bf16 in regs),
// B fragments straight from Wt (32 KB, L2-resident). No barriers.
__global__ __launch_bounds__(256) void gemm_pq(const float* __restrict__ x,
                                               const unsigned short* __restrict__ Wt,
                                               unsigned short* __restrict__ PQ,
                                               int n_nodes) {
  const int tid = threadIdx.x;
  const int wave = tid >> 6, lane = tid & 63;
  const int m = lane & 15, q = lane >> 4;
  const int row0 = blockIdx.x * 64 + wave * 16;   // 16 rows per wave

  // A row this lane streams (clamped so OOB lanes read row 0..n-1; stores guarded)
  const int arow = min(row0 + m, n_nodes - 1);
  const float* xr = x + (size_t)arow * NODE_DIM;

  // preload all 8 float4 (the lane's full 128-float row share) up front
  float4 av[4][2];
  #pragma unroll
  for (int kk = 0; kk < 4; kk++) {
    av[kk][0] = *(const float4*)&xr[kk * 32 + q * 8];
    av[kk][1] = *(const float4*)&xr[kk * 32 + q * 8 + 4];
  }

  f32x4 acc[8];
  #pragma unroll
  for (int t = 0; t < 8; t++) acc[t] = f32x4{0.f, 0.f, 0.f, 0.f};

  #pragma unroll
  for (int kk = 0; kk < 4; kk++) {
    // A[m = lane&15][k = kk*32 + q*8 + j]  (verified layout, round 1)
    union { unsigned short s[8]; u16x8 v; } au;
    au.s[0] = f2bf(av[kk][0].x); au.s[1] = f2bf(av[kk][0].y);
    au.s[2] = f2bf(av[kk][0].z); au.s[3] = f2bf(av[kk][0].w);
    au.s[4] = f2bf(av[kk][1].x); au.s[5] = f2bf(av[kk][1].y);
    au.s[6] = f2bf(av[kk][1].z); au.s[7] = f2bf(av[kk][1].w);
    bf16x8 a = __builtin_bit_cast(bf16x8, au.v);
    #pragma unroll
    for (int t = 0; t < 8; t++) {
      // B[k][n = t*16 + m]: Wt row (t*16+m), k-contiguous -> single 16B load
      bf16x8 b = __builtin_bit_cast(
          bf16x8, *(const u16x8*)&Wt[(size_t)(t * 16 + m) * 128 + kk * 32 + q * 8]);
      acc[t] = __builtin_amdgcn_mfma_f32_16x16x32_bf16(a, b, acc[t], 0, 0, 0);
    }
  }

  // C/D: col = t*16 + (lane&15), row = q*4 + reg  (verified round 1)
  #pragma unroll
  for (int t = 0; t < 8; t++) {
    #pragma unroll
    for (int r = 0; r < 4; r++) {
      int gr = row0 + q * 4 + r;
      if (gr < n_nodes) PQ[(size_t)gr * 128 + t * 16 + m] = f2bf(acc[t][r]);
    }
  }
}

// Exact grid: one 8-lane group per edge, no loop -> max outstanding gathers.
__global__ __launch_bounds__(256) void edge_mlp(const int* __restrict__ ei,
                                                const unsigned short* __restrict__ PQ,
                                                const float* __restrict__ b1,
                                                const float* __restrict__ W2,
                                                const float* __restrict__ b2,
                                                float* __restrict__ out, int E) {
  const int t = blockIdx.x * 256 + threadIdx.x;
  const int e = t >> 3, l = t & 7;
  if (e >= E) return;
  const int row = ei[e];
  const int col = ei[E + e];
  u16x8 pu = *(const u16x8*)&PQ[(size_t)row * 128 + l * 8];
  u16x8 qu = *(const u16x8*)&PQ[(size_t)col * 128 + 64 + l * 8];
  float partial = 0.f;
  #pragma unroll
  for (int i = 0; i < 8; i++) {
    float h = bf2f(pu[i]) + bf2f(qu[i]) + b1[l * 8 + i];
    h = fmaxf(h, 0.f);
    partial = fmaf(h, W2[l * 8 + i], partial);
  }
  partial += __shfl_xor(partial, 1);
  partial += __shfl_xor(partial, 2);
  partial += __shfl_xor(partial, 4);
  if (l == 0) out[e] = 1.f / (1.f + __expf(-(partial + b2[0])));
}

extern "C" void kernel_launch(void* const* d_in, const int* in_sizes, int n_in,
                              void* d_out, int out_size, void* d_ws, size_t ws_size,
                              hipStream_t stream) {
  const float* x  = (const float*)d_in[0];
  const int*   ei = (const int*)d_in[1];
  const float* W1 = (const float*)d_in[2];
  const float* b1 = (const float*)d_in[3];
  const float* W2 = (const float*)d_in[4];
  const float* b2 = (const float*)d_in[5];
  float* out = (float*)d_out;
  const int n_nodes = in_sizes[0] / NODE_DIM;
  const int E = in_sizes[1] / 2;

  // ws: Wt bf16 [128*128] @ 0 (32 KB), PQ bf16 [n_nodes*128] @ 32768 (25.6 MB)
  unsigned short* Wt = (unsigned short*)d_ws;
  unsigned short* PQ = (unsigned short*)((char*)d_ws + 32768);

  prep_wt<<<16, 256, 0, stream>>>(W1, Wt);
  gemm_pq<<<(n_nodes + 63) / 64, 256, 0, stream>>>(x, Wt, PQ, n_nodes);
  const int egrid = (E * 8 + 255) / 256;
  edge_mlp<<<egrid, 256, 0, stream>>>(ei, PQ, b1, W2, b2, out, E);
}

// Round 3
// 134.084 us; speedup vs baseline: 1.0839x; 1.0839x over previous
//
#include <hip/hip_runtime.h>
#include <hip/hip_bf16.h>

typedef unsigned short u16x8 __attribute__((ext_vector_type(8)));
typedef __bf16 bf16x8 __attribute__((ext_vector_type(8)));
typedef float f32x4 __attribute__((ext_vector_type(4)));

#define NODE_DIM 128
#define HID 64
#define LPAD 136   // +8 u16 pad: 2-way bank alias (free), keeps 16B-ish alignment at 8B

__device__ __forceinline__ unsigned short f2bf(float f) {
  union { float f; unsigned int u; } v; v.f = f;
  unsigned int u = v.u;
  u += 0x7fffu + ((u >> 16) & 1u);   // round-to-nearest-even
  return (unsigned short)(u >> 16);
}
__device__ __forceinline__ float bf2f(unsigned short s) {
  union { unsigned int u; float f; } v; v.u = ((unsigned int)s) << 16;
  return v.f;
}

// PQ[n][j] = sum_k x[n][k] * Wt[j][k], Wt[j][k] = W1 transposed+split (see below).
// Fused: each block transposes W1 (fp32, L2-resident) -> bf16 LDS, then runs
// 2 steps of 64 rows. A fragments direct from global x; B fragments from LDS.
__global__ __launch_bounds__(256) void gemm_pq(const float* __restrict__ x,
                                               const float* __restrict__ W1,
                                               unsigned short* __restrict__ PQ,
                                               int n_nodes) {
  __shared__ unsigned short bs[128][LPAD];  // bs[j][k]: j = out col, k = contig K
  const int tid = threadIdx.x;

  // Stage W1 (256x64 row-major fp32) transposed into bs[j][k]:
  //   j<64 : W1[k][j],  j>=64: W1[k+128][j-64]
  // Consecutive tid -> consecutive j -> coalesced W1 row reads.
  for (int i = tid; i < 128 * 128; i += 256) {
    int k = i >> 7, j = i & 127;
    float w = (j < 64) ? W1[k * 64 + j] : W1[(k + 128) * 64 + (j - 64)];
    bs[j][k] = f2bf(w);
  }
  __syncthreads();

  const int wave = tid >> 6, lane = tid & 63;
  const int m = lane & 15, q = lane >> 4;

  #pragma unroll
  for (int step = 0; step < 2; ++step) {
    const int row0 = blockIdx.x * 128 + step * 64 + wave * 16;  // 16 rows/wave
    if (row0 >= n_nodes) break;
    const int arow = min(row0 + m, n_nodes - 1);
    const float* xr = x + (size_t)arow * NODE_DIM;

    // Lane's full A share: 8 float4 (32 floats of its row), preloaded for ILP
    float4 av[4][2];
    #pragma unroll
    for (int kk = 0; kk < 4; kk++) {
      av[kk][0] = *(const float4*)&xr[kk * 32 + q * 8];
      av[kk][1] = *(const float4*)&xr[kk * 32 + q * 8 + 4];
    }

    f32x4 acc[8];
    #pragma unroll
    for (int t = 0; t < 8; t++) acc[t] = f32x4{0.f, 0.f, 0.f, 0.f};

    #pragma unroll
    for (int kk = 0; kk < 4; kk++) {
      // A[m = lane&15][k = kk*32 + q*8 + j]  (layout verified R1)
      union { unsigned short s[8]; u16x8 v; } au;
      au.s[0] = f2bf(av[kk][0].x); au.s[1] = f2bf(av[kk][0].y);
      au.s[2] = f2bf(av[kk][0].z); au.s[3] = f2bf(av[kk][0].w);
      au.s[4] = f2bf(av[kk][1].x); au.s[5] = f2bf(av[kk][1].y);
      au.s[6] = f2bf(av[kk][1].z); au.s[7] = f2bf(av[kk][1].w);
      bf16x8 a = __builtin_bit_cast(bf16x8, au.v);
      #pragma unroll
      for (int t = 0; t < 8; t++) {
        // B[k][n = t*16 + m] from LDS, k-contiguous 16B
        bf16x8 b = __builtin_bit_cast(bf16x8,
            *(const u16x8*)&bs[t * 16 + m][kk * 32 + q * 8]);
        acc[t] = __builtin_amdgcn_mfma_f32_16x16x32_bf16(a, b, acc[t], 0, 0, 0);
      }
    }

    // C/D: col = t*16 + (lane&15), row = q*4 + reg  (verified R1)
    #pragma unroll
    for (int t = 0; t < 8; t++) {
      #pragma unroll
      for (int r = 0; r < 4; r++) {
        int gr = row0 + q * 4 + r;
        if (gr < n_nodes) PQ[(size_t)gr * 128 + t * 16 + m] = f2bf(acc[t][r]);
      }
    }
  }
}

// Exact grid: one 8-lane group per edge, max outstanding gathers.
__global__ __launch_bounds__(256) void edge_mlp(const int* __restrict__ ei,
                                                const unsigned short* __restrict__ PQ,
                                                const float* __restrict__ b1,
                                                const float* __restrict__ W2,
                                                const float* __restrict__ b2,
                                                float* __restrict__ out, int E) {
  const int t = blockIdx.x * 256 + threadIdx.x;
  const int e = t >> 3, l = t & 7;
  if (e >= E) return;
  const int row = ei[e];
  const int col = ei[E + e];
  u16x8 pu = *(const u16x8*)&PQ[(size_t)row * 128 + l * 8];
  u16x8 qu = *(const u16x8*)&PQ[(size_t)col * 128 + 64 + l * 8];
  float partial = 0.f;
  #pragma unroll
  for (int i = 0; i < 8; i++) {
    float h = bf2f(pu[i]) + bf2f(qu[i]) + b1[l * 8 + i];
    h = fmaxf(h, 0.f);
    partial = fmaf(h, W2[l * 8 + i], partial);
  }
  partial += __shfl_xor(partial, 1);
  partial += __shfl_xor(partial, 2);
  partial += __shfl_xor(partial, 4);
  if (l == 0) out[e] = 1.f / (1.f + __expf(-(partial + b2[0])));
}

extern "C" void kernel_launch(void* const* d_in, const int* in_sizes, int n_in,
                              void* d_out, int out_size, void* d_ws, size_t ws_size,
                              hipStream_t stream) {
  const float* x  = (const float*)d_in[0];
  const int*   ei = (const int*)d_in[1];
  const float* W1 = (const float*)d_in[2];
  const float* b1 = (const float*)d_in[3];
  const float* W2 = (const float*)d_in[4];
  const float* b2 = (const float*)d_in[5];
  float* out = (float*)d_out;
  const int n_nodes = in_sizes[0] / NODE_DIM;
  const int E = in_sizes[1] / 2;

  // ws: PQ bf16 [n_nodes*128] @ 0 (25.6 MB)
  unsigned short* PQ = (unsigned short*)d_ws;

  gemm_pq<<<(n_nodes + 127) / 128, 256, 0, stream>>>(x, W1, PQ, n_nodes);
  const int egrid = (E * 8 + 255) / 256;
  edge_mlp<<<egrid, 256, 0, stream>>>(ei, PQ, b1, W2, b2, out, E);
}

// Round 5
// 128.535 us; speedup vs baseline: 1.1306x; 1.0432x over previous
//
#include <hip/hip_runtime.h>
#include <hip/hip_bf16.h>

typedef unsigned short u16x8 __attribute__((ext_vector_type(8)));
typedef __bf16 bf16x8 __attribute__((ext_vector_type(8)));
typedef float f32x4 __attribute__((ext_vector_type(4)));

#define NODE_DIM 128
#define LPAD 136   // +8 u16 pad: 2-way bank alias only (free per m136)

__device__ __forceinline__ unsigned short f2bf(float f) {
  union { float f; unsigned int u; } v; v.f = f;
  unsigned int u = v.u;
  u += 0x7fffu + ((u >> 16) & 1u);   // RNE
  return (unsigned short)(u >> 16);
}
__device__ __forceinline__ float bf2f(unsigned short s) {
  union { unsigned int u; float f; } v; v.u = ((unsigned int)s) << 16;
  return v.f;
}

// W1 (256x64 row-major fp32) -> Wt[j][k] bf16, j,k in [0,128):
//   j<64 : W1[k][j],  j>=64: W1[k+128][j-64]   (k-contiguous)
__global__ void prep_wt(const float* __restrict__ W1, unsigned short* __restrict__ Wt) {
  for (int i = blockIdx.x * blockDim.x + threadIdx.x; i < 128 * 128;
       i += gridDim.x * blockDim.x) {
    int j = i >> 7, k = i & 127;
    float w = (j < 64) ? W1[k * 64 + j] : W1[(k + 128) * 64 + (j - 64)];
    Wt[i] = f2bf(w);
  }
}

// PQ[n][j] = sum_k x[n][k] * Wt[j][k]
// B from LDS (staged once per block, 34.8 KB -> 4 blocks/CU);
// A direct from global, f2bf in regs (R2-proven); 2 x 64-row steps/block.
__global__ __launch_bounds__(256) void gemm_pq(const float* __restrict__ x,
                                               const unsigned short* __restrict__ Wt,
                                               unsigned short* __restrict__ PQ,
                                               int n_nodes) {
  __shared__ unsigned short bs[128][LPAD];
  const int tid = threadIdx.x;

  // Wt bf16 -> bs: 16B chunks, coalesced (8 iters/thread)
  for (int i = tid; i < 128 * 16; i += 256) {
    int j = i >> 4, c = i & 15;
    *(u16x8*)&bs[j][c * 8] = *(const u16x8*)&Wt[j * 128 + c * 8];
  }
  __syncthreads();

  const int wave = tid >> 6, lane = tid & 63;
  const int m = lane & 15, q = lane >> 4;

  #pragma unroll
  for (int step = 0; step < 2; ++step) {
    const int row0 = blockIdx.x * 128 + step * 64 + wave * 16;  // 16 rows/wave
    if (row0 < n_nodes) {
      const int arow = min(row0 + m, n_nodes - 1);  // OOB lanes clamp; stores guarded
      const float* xr = x + (size_t)arow * NODE_DIM;

      // lane's full A share: 8 float4, all issued before first use
      float4 av[4][2];
      #pragma unroll
      for (int kk = 0; kk < 4; kk++) {
        av[kk][0] = *(const float4*)&xr[kk * 32 + q * 8];
        av[kk][1] = *(const float4*)&xr[kk * 32 + q * 8 + 4];
      }

      f32x4 acc[8];
      #pragma unroll
      for (int t = 0; t < 8; t++) acc[t] = f32x4{0.f, 0.f, 0.f, 0.f};

      #pragma unroll
      for (int kk = 0; kk < 4; kk++) {
        // A[m = lane&15][k = kk*32 + q*8 + j]  (layout + this build proven R2)
        union { unsigned short s[8]; u16x8 v; } au;
        au.s[0] = f2bf(av[kk][0].x); au.s[1] = f2bf(av[kk][0].y);
        au.s[2] = f2bf(av[kk][0].z); au.s[3] = f2bf(av[kk][0].w);
        au.s[4] = f2bf(av[kk][1].x); au.s[5] = f2bf(av[kk][1].y);
        au.s[6] = f2bf(av[kk][1].z); au.s[7] = f2bf(av[kk][1].w);
        bf16x8 a = __builtin_bit_cast(bf16x8, au.v);
        #pragma unroll
        for (int t = 0; t < 8; t++) {
          // B[k][n = t*16 + m] from LDS, k-contiguous 16B (proven R1)
          bf16x8 b = __builtin_bit_cast(bf16x8,
              *(const u16x8*)&bs[t * 16 + m][kk * 32 + q * 8]);
          acc[t] = __builtin_amdgcn_mfma_f32_16x16x32_bf16(a, b, acc[t], 0, 0, 0);
        }
      }

      // C/D: col = t*16 + (lane&15), row = q*4 + reg  (proven R1)
      #pragma unroll
      for (int t = 0; t < 8; t++) {
        #pragma unroll
        for (int r = 0; r < 4; r++) {
          int gr = row0 + q * 4 + r;
          if (gr < n_nodes) PQ[(size_t)gr * 128 + t * 16 + m] = f2bf(acc[t][r]);
        }
      }
    }
  }
}

// Exact grid, 8 lanes/edge (verbatim from passing R3)
__global__ __launch_bounds__(256) void edge_mlp(const int* __restrict__ ei,
                                                const unsigned short* __restrict__ PQ,
                                                const float* __restrict__ b1,
                                                const float* __restrict__ W2,
                                                const float* __restrict__ b2,
                                                float* __restrict__ out, int E) {
  const int t = blockIdx.x * 256 + threadIdx.x;
  const int e = t >> 3, l = t & 7;
  if (e >= E) return;
  const int row = ei[e];
  const int col = ei[E + e];
  u16x8 pu = *(const u16x8*)&PQ[(size_t)row * 128 + l * 8];
  u16x8 qu = *(const u16x8*)&PQ[(size_t)col * 128 + 64 + l * 8];
  float partial = 0.f;
  #pragma unroll
  for (int i = 0; i < 8; i++) {
    float h = bf2f(pu[i]) + bf2f(qu[i]) + b1[l * 8 + i];
    h = fmaxf(h, 0.f);
    partial = fmaf(h, W2[l * 8 + i], partial);
  }
  partial += __shfl_xor(partial, 1);
  partial += __shfl_xor(partial, 2);
  partial += __shfl_xor(partial, 4);
  if (l == 0) out[e] = 1.f / (1.f + __expf(-(partial + b2[0])));
}

extern "C" void kernel_launch(void* const* d_in, const int* in_sizes, int n_in,
                              void* d_out, int out_size, void* d_ws, size_t ws_size,
                              hipStream_t stream) {
  const float* x  = (const float*)d_in[0];
  const int*   ei = (const int*)d_in[1];
  const float* W1 = (const float*)d_in[2];
  const float* b1 = (const float*)d_in[3];
  const float* W2 = (const float*)d_in[4];
  const float* b2 = (const float*)d_in[5];
  float* out = (float*)d_out;
  const int n_nodes = in_sizes[0] / NODE_DIM;
  const int E = in_sizes[1] / 2;

  // ws: Wt bf16 [128*128] @ 0 (32 KB), PQ bf16 [n_nodes*128] @ 32768 (25.6 MB)
  unsigned short* Wt = (unsigned short*)d_ws;
  unsigned short* PQ = (unsigned short*)((char*)d_ws + 32768);

  prep_wt<<<16, 256, 0, stream>>>(W1, Wt);
  gemm_pq<<<(n_nodes + 127) / 128, 256, 0, stream>>>(x, Wt, PQ, n_nodes);
  const int egrid = (E * 8 + 255) / 256;
  edge_mlp<<<egrid, 256, 0, stream>>>(ei, PQ, b1, W2, b2, out, E);
}